// Round 23
// baseline (156.341 us; speedup 1.0000x reference)
//
#include <hip/hip_runtime.h>
#include <stdint.h>

// Problem constants (B=2,S=1024,D=1024,F=4096,E=8)
#define T_TOK 2048
#define D_DIM 1024
#define F_DIM 4096
#define E_NUM 8
#define RPMAX 4096     // max padded rows at 256-alignment
#define BK 64
#define PITCH_W 4224   // W1 bf16 pitch (4096+128): 8448 B, non-pow2 -> no channel alias
#define PITCH_X 1088   // xg bf16 pitch (1024+64): 2176 B, non-pow2

typedef __attribute__((ext_vector_type(8))) short bfx8;   // 8 bf16 (4 VGPR)
typedef __attribute__((ext_vector_type(4))) float fx4;    // MFMA accum / staging

__device__ __forceinline__ unsigned short f2bf(float f) {
  union { float f; uint32_t u; } v; v.f = f;
  uint32_t u = v.u;
  u += 0x7FFFu + ((u >> 16) & 1u);   // round-to-nearest-even
  return (unsigned short)(u >> 16);
}

__device__ __forceinline__ void load_lds16(const unsigned short* g, unsigned short* l) {
  __builtin_amdgcn_global_load_lds(
      (const __attribute__((address_space(1))) void*)g,
      (__attribute__((address_space(3))) void*)l, 16, 0, 0);
}

__device__ __forceinline__ uint32_t cvtpk_bf16(float lo, float hi) {
  uint32_t d;
  asm("v_cvt_pk_bf16_f32 %0, %1, %2" : "=v"(d) : "v"(lo), "v"(hi));
  return d;
}

// ---------------- router: logits, softmax, argmax; NO global atomics ----------------
__global__ __launch_bounds__(256) void router_kernel(
    const float* __restrict__ x, const float* __restrict__ sw,
    const float* __restrict__ sb, float* __restrict__ pmax_out,
    int* __restrict__ routes, float* __restrict__ probs,
    unsigned short* __restrict__ xbf) {
  const int wave = threadIdx.x >> 6, lane = threadIdx.x & 63;
  const int t = blockIdx.x * 4 + wave;
  const float* xr = x + (size_t)t * D_DIM;
  float acc[8];
#pragma unroll
  for (int e = 0; e < 8; ++e) acc[e] = 0.f;
#pragma unroll
  for (int i = 0; i < 4; ++i) {
    const int d = i * 256 + lane * 4;
    float4 xv = *(const float4*)(xr + d);
    ushort4 h;
    h.x = f2bf(xv.x); h.y = f2bf(xv.y); h.z = f2bf(xv.z); h.w = f2bf(xv.w);
    *(ushort4*)(xbf + (size_t)t * D_DIM + d) = h;
    const float xs[4] = {xv.x, xv.y, xv.z, xv.w};
#pragma unroll
    for (int j = 0; j < 4; ++j) {
      const float4* swp = (const float4*)(sw + (size_t)(d + j) * 8);
      float4 w0 = swp[0], w1 = swp[1];
      acc[0] += xs[j] * w0.x; acc[1] += xs[j] * w0.y;
      acc[2] += xs[j] * w0.z; acc[3] += xs[j] * w0.w;
      acc[4] += xs[j] * w1.x; acc[5] += xs[j] * w1.y;
      acc[6] += xs[j] * w1.z; acc[7] += xs[j] * w1.w;
    }
  }
#pragma unroll
  for (int e = 0; e < 8; ++e) {
    float v = acc[e];
    for (int o = 32; o > 0; o >>= 1) v += __shfl_down(v, o, 64);
    acc[e] = v;
  }
  if (lane == 0) {
#pragma unroll
    for (int e = 0; e < 8; ++e) acc[e] += sb[e];
    int am = 0; float mx = acc[0];
#pragma unroll
    for (int e = 1; e < 8; ++e) if (acc[e] > mx) { mx = acc[e]; am = e; }  // first-max wins
    float p[8]; float s = 0.f;
#pragma unroll
    for (int e = 0; e < 8; ++e) { p[e] = expf(acc[e] - mx); s += p[e]; }
    float inv = 1.0f / s;
    pmax_out[t] = inv;
    routes[t] = am;
#pragma unroll
    for (int e = 0; e < 8; ++e) probs[(size_t)t * 8 + e] = p[e] * inv;
  }
}

// -------- plan: counts/psums reduce, 256-aligned offsets, perm init, scatter --------
__global__ __launch_bounds__(256) void plan_kernel(
    const int* __restrict__ routes, const float* __restrict__ probs,
    int* __restrict__ off, int* __restrict__ perm_out, int* __restrict__ perm_src,
    float* __restrict__ out_counts, float* __restrict__ out_psums,
    float* __restrict__ out_zero) {
  __shared__ int cnt[8];
  __shared__ int cur[8];
  __shared__ int offs[9];
  __shared__ float red[256][8];
  const int tid = threadIdx.x;
  if (tid < 8) cnt[tid] = 0;
  for (int i = tid; i < RPMAX; i += 256) { perm_out[i] = -1; perm_src[i] = 0; }
  __syncthreads();
  float loc[8];
#pragma unroll
  for (int e = 0; e < 8; ++e) loc[e] = 0.f;
  for (int t = tid; t < T_TOK; t += 256) {
    atomicAdd(&cnt[routes[t]], 1);
    const float4* p = (const float4*)(probs + (size_t)t * 8);
    float4 a = p[0], b = p[1];
    loc[0] += a.x; loc[1] += a.y; loc[2] += a.z; loc[3] += a.w;
    loc[4] += b.x; loc[5] += b.y; loc[6] += b.z; loc[7] += b.w;
  }
#pragma unroll
  for (int e = 0; e < 8; ++e) red[tid][e] = loc[e];
  __syncthreads();
  for (int s = 128; s >= 1; s >>= 1) {
    if (tid < s) {
#pragma unroll
      for (int e = 0; e < 8; ++e) red[tid][e] += red[tid + s][e];
    }
    __syncthreads();
  }
  if (tid == 0) {
    int o = 0;
    for (int e = 0; e < 8; ++e) { offs[e] = o; o += ((cnt[e] + 255) >> 8) << 8; }
    offs[8] = o;
    *out_zero = 0.0f;
  }
  __syncthreads();
  if (tid < 9) off[tid] = offs[tid];
  if (tid < 8) {
    cur[tid] = offs[tid];
    out_counts[tid] = (float)cnt[tid];
    out_psums[tid] = red[0][tid];
  }
  __syncthreads();
  for (int t = tid; t < T_TOK; t += 256) {
    int e = routes[t];
    int pos = atomicAdd(&cur[e], 1);
    perm_out[pos] = t;
    perm_src[pos] = t;
  }
}

// ---------------- gather: xg[slot] = xbf[perm_src[slot]], pitch PITCH_X ----------------
__global__ __launch_bounds__(256) void gather_kernel(
    const unsigned short* __restrict__ xbf, const int* __restrict__ off,
    const int* __restrict__ perm_src, unsigned short* __restrict__ xg) {
  const int wave = threadIdx.x >> 6, lane = threadIdx.x & 63;
  const int row = blockIdx.x * 4 + wave;
  if (row >= off[8]) return;
  const int tok = perm_src[row];
  const bfx8* s = (const bfx8*)(xbf + (size_t)tok * D_DIM);
  bfx8* d = (bfx8*)(xg + (size_t)row * PITCH_X);
  d[lane] = s[lane];
  d[lane + 64] = s[lane + 64];
}

// -------- convb: W1 fp32 [E][K][4096] -> bf16 rows at pitch 4224 (non-pow2) --------
// Block = one k-row: reads 16 KB fully contiguous, writes 8 KB fully contiguous.
// The odd 8448-B row pitch de-aliases the GEMM's strided B-slice reads.
__global__ __launch_bounds__(256) void convb_kernel(
    const float* __restrict__ W, unsigned short* __restrict__ Wbf) {
  const size_t row = blockIdx.x;                 // e*1024 + k, 0..8191
  const float* src = W + row * F_DIM;
  unsigned short* dst = Wbf + row * PITCH_W;
  const int t = threadIdx.x;
#pragma unroll
  for (int s = 0; s < 4; ++s) {
    float4 v = *(const float4*)(src + s * 1024 + t * 4);
    ushort4 h;
    h.x = f2bf(v.x); h.y = f2bf(v.y); h.z = f2bf(v.z); h.w = f2bf(v.w);
    *(ushort4*)(dst + s * 1024 + t * 4) = h;
  }
}

// ---------------- reduce: out[tok] = (sum_kz P[kz][row] + b2[e]) * pmax[tok] ----------
__global__ __launch_bounds__(256) void reduce_kernel(
    const float* __restrict__ P, const int* __restrict__ off,
    const int* __restrict__ perm_out, const float* __restrict__ b2,
    const float* __restrict__ pmax, float* __restrict__ out) {
  const int row = blockIdx.x;
  if (row >= off[8]) return;
  const int tok = perm_out[row];
  if (tok < 0) return;
  int e = 0;
#pragma unroll
  for (int i = 1; i <= 7; ++i) if (row >= off[i]) e = i;
  const int col = threadIdx.x * 4;
  const size_t base = (size_t)row * D_DIM + col;
  float4 p0 = *(const float4*)(P + base);
  float4 p1 = *(const float4*)(P + (size_t)1 * RPMAX * D_DIM + base);
  float4 p2 = *(const float4*)(P + (size_t)2 * RPMAX * D_DIM + base);
  float4 p3 = *(const float4*)(P + (size_t)3 * RPMAX * D_DIM + base);
  float4 bv = *(const float4*)(b2 + (size_t)e * D_DIM + col);
  const float pm = pmax[tok];
  float4 r;
  r.x = (p0.x + p1.x + p2.x + p3.x + bv.x) * pm;
  r.y = (p0.y + p1.y + p2.y + p3.y + bv.y) * pm;
  r.z = (p0.z + p1.z + p2.z + p3.z + bv.z) * pm;
  r.w = (p0.w + p1.w + p2.w + p3.w + bv.w) * pm;
  *(float4*)(out + (size_t)tok * D_DIM + col) = r;
}

// ---------------- GEMM1: 128x128 single-buffer, bf16-B from odd-pitch Wbf ----------
// Compacted 1-D grid (all CUs, ~2-4 blocks/CU). 8 waves (2m x 4n), wave 64x32,
// 32 KB LDS. B: ushort4 loads from Wbf (pitch 4224) -> bit-pack -> swizzled
// ds_write. A: xg (pitch 1088) via global_load_lds, pre-swizzled source.
template <int K_, int N_>
__global__ __launch_bounds__(512, 4) void gemm1s(
    const unsigned short* __restrict__ A,    // xg [RP][PITCH_X]
    const unsigned short* __restrict__ Wbf,  // [E][K_][PITCH_W] bf16
    const float* __restrict__ Bias,          // [E][N_]
    const int* __restrict__ off,
    unsigned short* __restrict__ Hout) {
  constexpr int BM = 128, BN = 128;
  constexpr int NT = K_ / BK;                // 16
  constexpr int FM = 4, FN = 2;
  constexpr int NBX = N_ / BN;               // 32
  __shared__ __align__(16) unsigned short As[BM * 64];   // 16 KB
  __shared__ __align__(16) unsigned short Bs[BN * 64];   // 16 KB
  const int tid = threadIdx.x;
  const int bid = blockIdx.x;
  const int live_by = off[8] >> 7;           // even
  const int live = live_by * NBX;            // mult of 64
  if (bid >= live) return;
  const int chunk = live >> 3;
  const int newlin = (bid & 7) * chunk + (bid >> 3);   // bijective in [0,live)
  const int bx = newlin / live_by;
  const int by = newlin % live_by;
  const int rowbase = by * BM;
  int e = 0;
#pragma unroll
  for (int i = 1; i <= 7; ++i) if (rowbase >= off[i]) e = i;
  const int n0 = bx * BN;
  const int wave = tid >> 6, lane = tid & 63;
  const int wm = wave >> 2, wn = wave & 3;
  const unsigned short* Wn0 = Wbf + (size_t)e * K_ * PITCH_W + n0;

  const unsigned short* aSrc[2];
#pragma unroll
  for (int c = 0; c < 2; ++c) {
    int ca = (wave * 2 + c) * 64 + lane;
    int row = ca >> 3, slot = ca & 7;
    int sc = slot ^ (row & 7);
    aSrc[c] = A + (size_t)(rowbase + row) * PITCH_X + sc * 8;
  }

  const int nq = lane & 15;
  const int qg = lane >> 4;
  const int kq = (qg & 1) * 4;
  const int cb = qg >> 1;                    // col-block 0..1
  ushort4 bu[4];

  fx4 acc[FM][FN];
#pragma unroll
  for (int a = 0; a < FM; ++a)
#pragma unroll
    for (int b = 0; b < FN; ++b) acc[a][b] = (fx4){0.f, 0.f, 0.f, 0.f};

  for (int t = 0; t < NT; ++t) {
    const int kt = t * BK;
#pragma unroll
    for (int c = 0; c < 2; ++c)
      load_lds16(aSrc[c] + kt, As + (wave * 2 + c) * 512);
#pragma unroll
    for (int j = 0; j < 4; ++j)
      bu[j] = *(const ushort4*)(Wn0 + (size_t)(kt + wave * 8 + kq + j) * PITCH_W +
                                cb * 64 + nq * 4);
#pragma unroll
    for (int i = 0; i < 4; ++i) {
      const int nl = cb * 64 + nq * 4 + i;
      const int key = ((nl >> 2) + 2 * (nl & 3)) & 7;
      const unsigned short* p0 = (const unsigned short*)&bu[0];
      const unsigned short* p1 = (const unsigned short*)&bu[1];
      const unsigned short* p2 = (const unsigned short*)&bu[2];
      const unsigned short* p3 = (const unsigned short*)&bu[3];
      uint32_t d0 = (uint32_t)p0[i] | ((uint32_t)p1[i] << 16);
      uint32_t d1 = (uint32_t)p2[i] | ((uint32_t)p3[i] << 16);
      *(uint2*)(Bs + nl * 64 + (wave ^ key) * 8 + kq) = make_uint2(d0, d1);
    }
    __syncthreads();
#pragma unroll
    for (int kk = 0; kk < 2; ++kk) {
      bfx8 af[FM], bf[FN];
#pragma unroll
      for (int fm = 0; fm < FM; ++fm) {
        int r = wm * 64 + fm * 16 + (lane & 15);
        int c = (kk * 4 + (lane >> 4)) ^ (r & 7);
        af[fm] = *(const bfx8*)(As + r * 64 + c * 8);
      }
#pragma unroll
      for (int fn = 0; fn < FN; ++fn) {
        int nn = wn * 32 + fn * 16 + (lane & 15);
        int key = ((nn >> 2) + 2 * (nn & 3)) & 7;
        int c = (kk * 4 + (lane >> 4)) ^ key;
        bf[fn] = *(const bfx8*)(Bs + nn * 64 + c * 8);
      }
#pragma unroll
      for (int fm = 0; fm < FM; ++fm)
#pragma unroll
        for (int fn = 0; fn < FN; ++fn)
          acc[fm][fn] = __builtin_amdgcn_mfma_f32_16x16x32_bf16(
              af[fm], bf[fn], acc[fm][fn], 0, 0, 0);
    }
    __syncthreads();
  }

  // ---- epilogue: relu(acc + b1) -> H bf16 ----
  const int colbase = n0 + wn * 32;
#pragma unroll
  for (int fn = 0; fn < FN; ++fn) {
    int colg = colbase + fn * 16 + (lane & 15);
    float bv = Bias[(size_t)e * N_ + colg];
#pragma unroll
    for (int fm = 0; fm < FM; ++fm) {
      int rg = rowbase + wm * 64 + fm * 16 + ((lane >> 4) << 2);
#pragma unroll
      for (int j = 0; j < 4; ++j) {
        float v = fmaxf(acc[fm][fn][j] + bv, 0.f);
        Hout[(size_t)(rg + j) * N_ + colg] = f2bf(v);
      }
    }
  }
}

// ---------------- GEMM2: 128x256 single-buffer, fused fp32-B, compacted grid ---------
template <int K_, int N_, int KSPLIT>
__global__ __launch_bounds__(512, 4) void gemm2s(
    const unsigned short* __restrict__ A,    // H [RP][K_]
    const float* __restrict__ W,             // [E][K_][N_] fp32
    const int* __restrict__ off,
    float* __restrict__ Pout) {
  constexpr int BM = 128, BN = 256;
  constexpr int KS = K_ / KSPLIT;
  constexpr int NT = KS / BK;
  constexpr int FM = 4, FN = 4, GRP = 2;
  constexpr int NBX = N_ / BN;               // 4
  __shared__ __align__(16) unsigned short As[BM * 64];   // 16 KB
  __shared__ __align__(16) unsigned short Bs[BN * 64];   // 32 KB
  const int tid = threadIdx.x;
  const int bid = blockIdx.x;
  const int live_by = off[8] >> 7;
  const int live = live_by * NBX * KSPLIT;   // mult of 32
  if (bid >= live) return;
  const int chunk = live >> 3;
  const int newlin = (bid & 7) * chunk + (bid >> 3);
  const int bx = newlin / (live_by * KSPLIT);
  const int rem = newlin % (live_by * KSPLIT);
  const int by = rem % live_by;
  const int kz = rem / live_by;
  const int rowbase = by * BM;
  int e = 0;
#pragma unroll
  for (int i = 1; i <= 7; ++i) if (rowbase >= off[i]) e = i;
  const int n0 = bx * BN;
  const int k0base = kz * KS;
  const int wave = tid >> 6, lane = tid & 63;
  const int wm = wave >> 2, wn = wave & 3;
  const float* Wn0 = W + (size_t)e * K_ * N_ + n0;

  const unsigned short* aSrc[2];
#pragma unroll
  for (int c = 0; c < 2; ++c) {
    int ca = (wave * 2 + c) * 64 + lane;
    int row = ca >> 3, slot = ca & 7;
    int sc = slot ^ (row & 7);
    aSrc[c] = A + (size_t)(rowbase + row) * K_ + k0base + sc * 8;
  }

  const int nq = lane & 15;
  const int qg = lane >> 4;
  const int kq = (qg & 1) * 4;
  fx4 br[GRP][4];

  fx4 acc[FM][FN];
#pragma unroll
  for (int a = 0; a < FM; ++a)
#pragma unroll
    for (int b = 0; b < FN; ++b) acc[a][b] = (fx4){0.f, 0.f, 0.f, 0.f};

  for (int t = 0; t < NT; ++t) {
    const int kt = t * BK;
#pragma unroll
    for (int c = 0; c < 2; ++c)
      load_lds16(aSrc[c] + kt, As + (wave * 2 + c) * 512);
#pragma unroll
    for (int g = 0; g < GRP; ++g) {
      const int cb = g * 2 + (qg >> 1);
#pragma unroll
      for (int j = 0; j < 4; ++j)
        br[g][j] = *(const fx4*)(Wn0 + (size_t)(kt + wave * 8 + kq + j) * N_ +
                                 cb * 64 + nq * 4);
    }
#pragma unroll
    for (int g = 0; g < GRP; ++g) {
      const int cb = g * 2 + (qg >> 1);
#pragma unroll
      for (int i = 0; i < 4; ++i) {
        const int nl = cb * 64 + nq * 4 + i;
        const int key = ((nl >> 2) + 2 * (nl & 3)) & 7;
        uint32_t d0 = cvtpk_bf16(br[g][0][i], br[g][1][i]);
        uint32_t d1 = cvtpk_bf16(br[g][2][i], br[g][3][i]);
        *(uint2*)(Bs + nl * 64 + (wave ^ key) * 8 + kq) = make_uint2(d0, d1);
      }
    }
    __syncthreads();
#pragma unroll
    for (int kk = 0; kk < 2; ++kk) {
      bfx8 af[FM], bf[FN];
#pragma unroll
      for (int fm = 0; fm < FM; ++fm) {
        int r = wm * 64 + fm * 16 + (lane & 15);
        int c = (kk * 4 + (lane >> 4)) ^ (r & 7);
        af[fm] = *(const bfx8*)(As + r * 64 + c * 8);
      }
#pragma unroll
      for (int fn = 0; fn < FN; ++fn) {
        int nn = wn * 64 + fn * 16 + (lane & 15);
        int key = ((nn >> 2) + 2 * (nn & 3)) & 7;
        int c = (kk * 4 + (lane >> 4)) ^ key;
        bf[fn] = *(const bfx8*)(Bs + nn * 64 + c * 8);
      }
#pragma unroll
      for (int fm = 0; fm < FM; ++fm)
#pragma unroll
        for (int fn = 0; fn < FN; ++fn)
          acc[fm][fn] = __builtin_amdgcn_mfma_f32_16x16x32_bf16(
              af[fm], bf[fn], acc[fm][fn], 0, 0, 0);
    }
    __syncthreads();
  }

  const int colbase = n0 + wn * 64;
  float* Pk = Pout + (size_t)kz * RPMAX * N_;
#pragma unroll
  for (int fm = 0; fm < FM; ++fm) {
    int rg = rowbase + wm * 64 + fm * 16 + ((lane >> 4) << 2);
#pragma unroll
    for (int j = 0; j < 4; ++j) {
#pragma unroll
      for (int fn = 0; fn < FN; ++fn) {
        int colg = colbase + fn * 16 + (lane & 15);
        Pk[(size_t)(rg + j) * N_ + colg] = acc[fm][fn][j];
      }
    }
  }
}

extern "C" void kernel_launch(void* const* d_in, const int* in_sizes, int n_in,
                              void* d_out, int out_size, void* d_ws, size_t ws_size,
                              hipStream_t stream) {
  const float* x  = (const float*)d_in[0];
  const float* sw = (const float*)d_in[1];
  const float* sb = (const float*)d_in[2];
  const float* w1 = (const float*)d_in[3];
  const float* b1 = (const float*)d_in[4];
  const float* w2 = (const float*)d_in[5];
  const float* b2 = (const float*)d_in[6];
  float* out = (float*)d_out;

  char* ws = (char*)d_ws;
  int*   off      = (int*)(ws + 0);          // 9 ints
  int*   routes   = (int*)(ws + 1024);       // 2048 ints
  int*   perm_out = (int*)(ws + 16384);      // RPMAX ints (pads -1)
  int*   perm_src = (int*)(ws + 32768);      // RPMAX ints (pads 0)
  float* probs    = (float*)(ws + 65536);    // 2048x8 fp32
  unsigned short* xbf = (unsigned short*)(ws + (1u << 20));    // 4 MB
  unsigned short* H   = (unsigned short*)(ws + (8u << 20));    // 32 MB (ends 40)
  unsigned short* xg  = (unsigned short*)(ws + (40u << 20));   // 4096x1088 bf16 = 8.9 MB
  // Wbf and P share [49 MB, 118 MB): Wbf dead after gemm1s; P born at gemm2s.
  unsigned short* Wbf = (unsigned short*)(ws + (49u << 20));   // 8x1024x4224 bf16 = 69 MB
  float* P            = (float*)(ws + (49u << 20));            // 4x4096x1024 fp32 = 64 MB

  // d_out layout: final(2097152) | counts(8) | psums(8) | 0(1) | pmax(2048)
  float* out_final  = out;
  float* out_counts = out + 2097152;
  float* out_psums  = out + 2097160;
  float* out_zero   = out + 2097168;
  float* out_pmax   = out + 2097169;

  router_kernel<<<T_TOK / 4, 256, 0, stream>>>(x, sw, sb, out_pmax, routes, probs, xbf);
  plan_kernel<<<1, 256, 0, stream>>>(routes, probs, off, perm_out, perm_src,
                                     out_counts, out_psums, out_zero);
  gather_kernel<<<RPMAX / 4, 256, 0, stream>>>(xbf, off, perm_src, xg);

  // convb: W1 -> bf16 at odd pitch (wide reads, wide writes; de-alias GEMM1 B)
  convb_kernel<<<E_NUM * D_DIM, 256, 0, stream>>>(w1, Wbf);

  // GEMM1: xg x Wbf -> H (relu, bf16). 128x128, compacted grid, odd-pitch B.
  gemm1s<D_DIM, F_DIM><<<1024, 512, 0, stream>>>(xg, Wbf, b1, off, H);
  // GEMM2: H x W2 -> fp32 partials P[4][RP][1024]. 128x256, split-K=4, compacted.
  gemm2s<F_DIM, D_DIM, 4><<<512, 512, 0, stream>>>(H, w2, off, P);
  // reduce: out[tok] = (sum_kz P + b2[e]) * pmax[tok], coalesced scatter.
  reduce_kernel<<<RPMAX, 256, 0, stream>>>(P, off, perm_out, b2, out_pmax, out_final);
}

// Round 24
// 155.257 us; speedup vs baseline: 1.0070x; 1.0070x over previous
//
#include <hip/hip_runtime.h>
#include <stdint.h>

// Problem constants (B=2,S=1024,D=1024,F=4096,E=8)
#define T_TOK 2048
#define D_DIM 1024
#define F_DIM 4096
#define E_NUM 8
#define RPMAX 4096     // max padded rows at 256-alignment
#define BK 64
// W1 bf16 row pitch: 4864 elems = 9728 B = 2^9 * 19. Channel-granule advance per
// k-row = 9728/G is NON-INTEGER (odd numerator) for G in {1,2,4} KB -> a K-step's
// 16-row read fan spreads over (nearly) all 32 channels instead of ~8.
// (R23's 8448 B = 2.0625 * 4096 drifted only 256 B/row -> same channel class.)
#define PITCH_W 4864
#define PITCH_X 1088   // xg bf16 pitch: 2176 B = 2^7 * 17 (same idea; A is L2-hot anyway)

typedef __attribute__((ext_vector_type(8))) short bfx8;   // 8 bf16 (4 VGPR)
typedef __attribute__((ext_vector_type(4))) float fx4;    // MFMA accum / staging

__device__ __forceinline__ unsigned short f2bf(float f) {
  union { float f; uint32_t u; } v; v.f = f;
  uint32_t u = v.u;
  u += 0x7FFFu + ((u >> 16) & 1u);   // round-to-nearest-even
  return (unsigned short)(u >> 16);
}

__device__ __forceinline__ void load_lds16(const unsigned short* g, unsigned short* l) {
  __builtin_amdgcn_global_load_lds(
      (const __attribute__((address_space(1))) void*)g,
      (__attribute__((address_space(3))) void*)l, 16, 0, 0);
}

__device__ __forceinline__ uint32_t cvtpk_bf16(float lo, float hi) {
  uint32_t d;
  asm("v_cvt_pk_bf16_f32 %0, %1, %2" : "=v"(d) : "v"(lo), "v"(hi));
  return d;
}

// ---------------- router: logits, softmax, argmax; NO global atomics ----------------
__global__ __launch_bounds__(256) void router_kernel(
    const float* __restrict__ x, const float* __restrict__ sw,
    const float* __restrict__ sb, float* __restrict__ pmax_out,
    int* __restrict__ routes, float* __restrict__ probs,
    unsigned short* __restrict__ xbf) {
  const int wave = threadIdx.x >> 6, lane = threadIdx.x & 63;
  const int t = blockIdx.x * 4 + wave;
  const float* xr = x + (size_t)t * D_DIM;
  float acc[8];
#pragma unroll
  for (int e = 0; e < 8; ++e) acc[e] = 0.f;
#pragma unroll
  for (int i = 0; i < 4; ++i) {
    const int d = i * 256 + lane * 4;
    float4 xv = *(const float4*)(xr + d);
    ushort4 h;
    h.x = f2bf(xv.x); h.y = f2bf(xv.y); h.z = f2bf(xv.z); h.w = f2bf(xv.w);
    *(ushort4*)(xbf + (size_t)t * D_DIM + d) = h;
    const float xs[4] = {xv.x, xv.y, xv.z, xv.w};
#pragma unroll
    for (int j = 0; j < 4; ++j) {
      const float4* swp = (const float4*)(sw + (size_t)(d + j) * 8);
      float4 w0 = swp[0], w1 = swp[1];
      acc[0] += xs[j] * w0.x; acc[1] += xs[j] * w0.y;
      acc[2] += xs[j] * w0.z; acc[3] += xs[j] * w0.w;
      acc[4] += xs[j] * w1.x; acc[5] += xs[j] * w1.y;
      acc[6] += xs[j] * w1.z; acc[7] += xs[j] * w1.w;
    }
  }
#pragma unroll
  for (int e = 0; e < 8; ++e) {
    float v = acc[e];
    for (int o = 32; o > 0; o >>= 1) v += __shfl_down(v, o, 64);
    acc[e] = v;
  }
  if (lane == 0) {
#pragma unroll
    for (int e = 0; e < 8; ++e) acc[e] += sb[e];
    int am = 0; float mx = acc[0];
#pragma unroll
    for (int e = 1; e < 8; ++e) if (acc[e] > mx) { mx = acc[e]; am = e; }  // first-max wins
    float p[8]; float s = 0.f;
#pragma unroll
    for (int e = 0; e < 8; ++e) { p[e] = expf(acc[e] - mx); s += p[e]; }
    float inv = 1.0f / s;
    pmax_out[t] = inv;
    routes[t] = am;
#pragma unroll
    for (int e = 0; e < 8; ++e) probs[(size_t)t * 8 + e] = p[e] * inv;
  }
}

// -------- plan: counts/psums reduce, 256-aligned offsets, perm init, scatter --------
__global__ __launch_bounds__(256) void plan_kernel(
    const int* __restrict__ routes, const float* __restrict__ probs,
    int* __restrict__ off, int* __restrict__ perm_out, int* __restrict__ perm_src,
    float* __restrict__ out_counts, float* __restrict__ out_psums,
    float* __restrict__ out_zero) {
  __shared__ int cnt[8];
  __shared__ int cur[8];
  __shared__ int offs[9];
  __shared__ float red[256][8];
  const int tid = threadIdx.x;
  if (tid < 8) cnt[tid] = 0;
  for (int i = tid; i < RPMAX; i += 256) { perm_out[i] = -1; perm_src[i] = 0; }
  __syncthreads();
  float loc[8];
#pragma unroll
  for (int e = 0; e < 8; ++e) loc[e] = 0.f;
  for (int t = tid; t < T_TOK; t += 256) {
    atomicAdd(&cnt[routes[t]], 1);
    const float4* p = (const float4*)(probs + (size_t)t * 8);
    float4 a = p[0], b = p[1];
    loc[0] += a.x; loc[1] += a.y; loc[2] += a.z; loc[3] += a.w;
    loc[4] += b.x; loc[5] += b.y; loc[6] += b.z; loc[7] += b.w;
  }
#pragma unroll
  for (int e = 0; e < 8; ++e) red[tid][e] = loc[e];
  __syncthreads();
  for (int s = 128; s >= 1; s >>= 1) {
    if (tid < s) {
#pragma unroll
      for (int e = 0; e < 8; ++e) red[tid][e] += red[tid + s][e];
    }
    __syncthreads();
  }
  if (tid == 0) {
    int o = 0;
    for (int e = 0; e < 8; ++e) { offs[e] = o; o += ((cnt[e] + 255) >> 8) << 8; }
    offs[8] = o;
    *out_zero = 0.0f;
  }
  __syncthreads();
  if (tid < 9) off[tid] = offs[tid];
  if (tid < 8) {
    cur[tid] = offs[tid];
    out_counts[tid] = (float)cnt[tid];
    out_psums[tid] = red[0][tid];
  }
  __syncthreads();
  for (int t = tid; t < T_TOK; t += 256) {
    int e = routes[t];
    int pos = atomicAdd(&cur[e], 1);
    perm_out[pos] = t;
    perm_src[pos] = t;
  }
}

// ---------------- gather: xg[slot] = xbf[perm_src[slot]], pitch PITCH_X ----------------
__global__ __launch_bounds__(256) void gather_kernel(
    const unsigned short* __restrict__ xbf, const int* __restrict__ off,
    const int* __restrict__ perm_src, unsigned short* __restrict__ xg) {
  const int wave = threadIdx.x >> 6, lane = threadIdx.x & 63;
  const int row = blockIdx.x * 4 + wave;
  if (row >= off[8]) return;
  const int tok = perm_src[row];
  const bfx8* s = (const bfx8*)(xbf + (size_t)tok * D_DIM);
  bfx8* d = (bfx8*)(xg + (size_t)row * PITCH_X);
  d[lane] = s[lane];
  d[lane + 64] = s[lane + 64];
}

// -------- convb: W1 fp32 [E][K][4096] -> bf16 rows at pitch 4864 (2^9*19) --------
// Block = one k-row: reads 16 KB fully contiguous, writes 8 KB fully contiguous.
__global__ __launch_bounds__(256) void convb_kernel(
    const float* __restrict__ W, unsigned short* __restrict__ Wbf) {
  const size_t row = blockIdx.x;                 // e*1024 + k, 0..8191
  const float* src = W + row * F_DIM;
  unsigned short* dst = Wbf + row * PITCH_W;
  const int t = threadIdx.x;
#pragma unroll
  for (int s = 0; s < 4; ++s) {
    float4 v = *(const float4*)(src + s * 1024 + t * 4);
    ushort4 h;
    h.x = f2bf(v.x); h.y = f2bf(v.y); h.z = f2bf(v.z); h.w = f2bf(v.w);
    *(ushort4*)(dst + s * 1024 + t * 4) = h;
  }
}

// ---------------- reduce: out[tok] = (sum_kz P[kz][row] + b2[e]) * pmax[tok] ----------
__global__ __launch_bounds__(256) void reduce_kernel(
    const float* __restrict__ P, const int* __restrict__ off,
    const int* __restrict__ perm_out, const float* __restrict__ b2,
    const float* __restrict__ pmax, float* __restrict__ out) {
  const int row = blockIdx.x;
  if (row >= off[8]) return;
  const int tok = perm_out[row];
  if (tok < 0) return;
  int e = 0;
#pragma unroll
  for (int i = 1; i <= 7; ++i) if (row >= off[i]) e = i;
  const int col = threadIdx.x * 4;
  const size_t base = (size_t)row * D_DIM + col;
  float4 p0 = *(const float4*)(P + base);
  float4 p1 = *(const float4*)(P + (size_t)1 * RPMAX * D_DIM + base);
  float4 p2 = *(const float4*)(P + (size_t)2 * RPMAX * D_DIM + base);
  float4 p3 = *(const float4*)(P + (size_t)3 * RPMAX * D_DIM + base);
  float4 bv = *(const float4*)(b2 + (size_t)e * D_DIM + col);
  const float pm = pmax[tok];
  float4 r;
  r.x = (p0.x + p1.x + p2.x + p3.x + bv.x) * pm;
  r.y = (p0.y + p1.y + p2.y + p3.y + bv.y) * pm;
  r.z = (p0.z + p1.z + p2.z + p3.z + bv.z) * pm;
  r.w = (p0.w + p1.w + p2.w + p3.w + bv.w) * pm;
  *(float4*)(out + (size_t)tok * D_DIM + col) = r;
}

// ---------------- GEMM1: 128x128 single-buffer, bf16-B from coprime-pitch Wbf -------
// Compacted 1-D grid (all CUs). 8 waves (2m x 4n), wave 64x32, 32 KB LDS.
// B: ushort4 loads from Wbf (pitch 4864 -> fractional channel-granule advance per
// k-row -> step's 16-row fan hits all channels). A: xg via global_load_lds.
template <int K_, int N_>
__global__ __launch_bounds__(512, 4) void gemm1s(
    const unsigned short* __restrict__ A,    // xg [RP][PITCH_X]
    const unsigned short* __restrict__ Wbf,  // [E][K_][PITCH_W] bf16
    const float* __restrict__ Bias,          // [E][N_]
    const int* __restrict__ off,
    unsigned short* __restrict__ Hout) {
  constexpr int BM = 128, BN = 128;
  constexpr int NT = K_ / BK;                // 16
  constexpr int FM = 4, FN = 2;
  constexpr int NBX = N_ / BN;               // 32
  __shared__ __align__(16) unsigned short As[BM * 64];   // 16 KB
  __shared__ __align__(16) unsigned short Bs[BN * 64];   // 16 KB
  const int tid = threadIdx.x;
  const int bid = blockIdx.x;
  const int live_by = off[8] >> 7;           // even
  const int live = live_by * NBX;            // mult of 64
  if (bid >= live) return;
  const int chunk = live >> 3;
  const int newlin = (bid & 7) * chunk + (bid >> 3);   // bijective in [0,live)
  const int bx = newlin / live_by;
  const int by = newlin % live_by;
  const int rowbase = by * BM;
  int e = 0;
#pragma unroll
  for (int i = 1; i <= 7; ++i) if (rowbase >= off[i]) e = i;
  const int n0 = bx * BN;
  const int wave = tid >> 6, lane = tid & 63;
  const int wm = wave >> 2, wn = wave & 3;
  const unsigned short* Wn0 = Wbf + (size_t)e * K_ * PITCH_W + n0;

  const unsigned short* aSrc[2];
#pragma unroll
  for (int c = 0; c < 2; ++c) {
    int ca = (wave * 2 + c) * 64 + lane;
    int row = ca >> 3, slot = ca & 7;
    int sc = slot ^ (row & 7);
    aSrc[c] = A + (size_t)(rowbase + row) * PITCH_X + sc * 8;
  }

  const int nq = lane & 15;
  const int qg = lane >> 4;
  const int kq = (qg & 1) * 4;
  const int cb = qg >> 1;                    // col-block 0..1
  ushort4 bu[4];

  fx4 acc[FM][FN];
#pragma unroll
  for (int a = 0; a < FM; ++a)
#pragma unroll
    for (int b = 0; b < FN; ++b) acc[a][b] = (fx4){0.f, 0.f, 0.f, 0.f};

  for (int t = 0; t < NT; ++t) {
    const int kt = t * BK;
#pragma unroll
    for (int c = 0; c < 2; ++c)
      load_lds16(aSrc[c] + kt, As + (wave * 2 + c) * 512);
#pragma unroll
    for (int j = 0; j < 4; ++j)
      bu[j] = *(const ushort4*)(Wn0 + (size_t)(kt + wave * 8 + kq + j) * PITCH_W +
                                cb * 64 + nq * 4);
#pragma unroll
    for (int i = 0; i < 4; ++i) {
      const int nl = cb * 64 + nq * 4 + i;
      const int key = ((nl >> 2) + 2 * (nl & 3)) & 7;
      const unsigned short* p0 = (const unsigned short*)&bu[0];
      const unsigned short* p1 = (const unsigned short*)&bu[1];
      const unsigned short* p2 = (const unsigned short*)&bu[2];
      const unsigned short* p3 = (const unsigned short*)&bu[3];
      uint32_t d0 = (uint32_t)p0[i] | ((uint32_t)p1[i] << 16);
      uint32_t d1 = (uint32_t)p2[i] | ((uint32_t)p3[i] << 16);
      *(uint2*)(Bs + nl * 64 + (wave ^ key) * 8 + kq) = make_uint2(d0, d1);
    }
    __syncthreads();
#pragma unroll
    for (int kk = 0; kk < 2; ++kk) {
      bfx8 af[FM], bf[FN];
#pragma unroll
      for (int fm = 0; fm < FM; ++fm) {
        int r = wm * 64 + fm * 16 + (lane & 15);
        int c = (kk * 4 + (lane >> 4)) ^ (r & 7);
        af[fm] = *(const bfx8*)(As + r * 64 + c * 8);
      }
#pragma unroll
      for (int fn = 0; fn < FN; ++fn) {
        int nn = wn * 32 + fn * 16 + (lane & 15);
        int key = ((nn >> 2) + 2 * (nn & 3)) & 7;
        int c = (kk * 4 + (lane >> 4)) ^ key;
        bf[fn] = *(const bfx8*)(Bs + nn * 64 + c * 8);
      }
#pragma unroll
      for (int fm = 0; fm < FM; ++fm)
#pragma unroll
        for (int fn = 0; fn < FN; ++fn)
          acc[fm][fn] = __builtin_amdgcn_mfma_f32_16x16x32_bf16(
              af[fm], bf[fn], acc[fm][fn], 0, 0, 0);
    }
    __syncthreads();
  }

  // ---- epilogue: relu(acc + b1) -> H bf16 ----
  const int colbase = n0 + wn * 32;
#pragma unroll
  for (int fn = 0; fn < FN; ++fn) {
    int colg = colbase + fn * 16 + (lane & 15);
    float bv = Bias[(size_t)e * N_ + colg];
#pragma unroll
    for (int fm = 0; fm < FM; ++fm) {
      int rg = rowbase + wm * 64 + fm * 16 + ((lane >> 4) << 2);
#pragma unroll
      for (int j = 0; j < 4; ++j) {
        float v = fmaxf(acc[fm][fn][j] + bv, 0.f);
        Hout[(size_t)(rg + j) * N_ + colg] = f2bf(v);
      }
    }
  }
}

// ---------------- GEMM2: 128x256 single-buffer, fused fp32-B, compacted grid ---------
template <int K_, int N_, int KSPLIT>
__global__ __launch_bounds__(512, 4) void gemm2s(
    const unsigned short* __restrict__ A,    // H [RP][K_]
    const float* __restrict__ W,             // [E][K_][N_] fp32
    const int* __restrict__ off,
    float* __restrict__ Pout) {
  constexpr int BM = 128, BN = 256;
  constexpr int KS = K_ / KSPLIT;
  constexpr int NT = KS / BK;
  constexpr int FM = 4, FN = 4, GRP = 2;
  constexpr int NBX = N_ / BN;               // 4
  __shared__ __align__(16) unsigned short As[BM * 64];   // 16 KB
  __shared__ __align__(16) unsigned short Bs[BN * 64];   // 32 KB
  const int tid = threadIdx.x;
  const int bid = blockIdx.x;
  const int live_by = off[8] >> 7;
  const int live = live_by * NBX * KSPLIT;   // mult of 32
  if (bid >= live) return;
  const int chunk = live >> 3;
  const int newlin = (bid & 7) * chunk + (bid >> 3);
  const int bx = newlin / (live_by * KSPLIT);
  const int rem = newlin % (live_by * KSPLIT);
  const int by = rem % live_by;
  const int kz = rem / live_by;
  const int rowbase = by * BM;
  int e = 0;
#pragma unroll
  for (int i = 1; i <= 7; ++i) if (rowbase >= off[i]) e = i;
  const int n0 = bx * BN;
  const int k0base = kz * KS;
  const int wave = tid >> 6, lane = tid & 63;
  const int wm = wave >> 2, wn = wave & 3;
  const float* Wn0 = W + (size_t)e * K_ * N_ + n0;

  const unsigned short* aSrc[2];
#pragma unroll
  for (int c = 0; c < 2; ++c) {
    int ca = (wave * 2 + c) * 64 + lane;
    int row = ca >> 3, slot = ca & 7;
    int sc = slot ^ (row & 7);
    aSrc[c] = A + (size_t)(rowbase + row) * K_ + k0base + sc * 8;
  }

  const int nq = lane & 15;
  const int qg = lane >> 4;
  const int kq = (qg & 1) * 4;
  fx4 br[GRP][4];

  fx4 acc[FM][FN];
#pragma unroll
  for (int a = 0; a < FM; ++a)
#pragma unroll
    for (int b = 0; b < FN; ++b) acc[a][b] = (fx4){0.f, 0.f, 0.f, 0.f};

  for (int t = 0; t < NT; ++t) {
    const int kt = t * BK;
#pragma unroll
    for (int c = 0; c < 2; ++c)
      load_lds16(aSrc[c] + kt, As + (wave * 2 + c) * 512);
#pragma unroll
    for (int g = 0; g < GRP; ++g) {
      const int cb = g * 2 + (qg >> 1);
#pragma unroll
      for (int j = 0; j < 4; ++j)
        br[g][j] = *(const fx4*)(Wn0 + (size_t)(kt + wave * 8 + kq + j) * N_ +
                                 cb * 64 + nq * 4);
    }
#pragma unroll
    for (int g = 0; g < GRP; ++g) {
      const int cb = g * 2 + (qg >> 1);
#pragma unroll
      for (int i = 0; i < 4; ++i) {
        const int nl = cb * 64 + nq * 4 + i;
        const int key = ((nl >> 2) + 2 * (nl & 3)) & 7;
        uint32_t d0 = cvtpk_bf16(br[g][0][i], br[g][1][i]);
        uint32_t d1 = cvtpk_bf16(br[g][2][i], br[g][3][i]);
        *(uint2*)(Bs + nl * 64 + (wave ^ key) * 8 + kq) = make_uint2(d0, d1);
      }
    }
    __syncthreads();
#pragma unroll
    for (int kk = 0; kk < 2; ++kk) {
      bfx8 af[FM], bf[FN];
#pragma unroll
      for (int fm = 0; fm < FM; ++fm) {
        int r = wm * 64 + fm * 16 + (lane & 15);
        int c = (kk * 4 + (lane >> 4)) ^ (r & 7);
        af[fm] = *(const bfx8*)(As + r * 64 + c * 8);
      }
#pragma unroll
      for (int fn = 0; fn < FN; ++fn) {
        int nn = wn * 64 + fn * 16 + (lane & 15);
        int key = ((nn >> 2) + 2 * (nn & 3)) & 7;
        int c = (kk * 4 + (lane >> 4)) ^ key;
        bf[fn] = *(const bfx8*)(Bs + nn * 64 + c * 8);
      }
#pragma unroll
      for (int fm = 0; fm < FM; ++fm)
#pragma unroll
        for (int fn = 0; fn < FN; ++fn)
          acc[fm][fn] = __builtin_amdgcn_mfma_f32_16x16x32_bf16(
              af[fm], bf[fn], acc[fm][fn], 0, 0, 0);
    }
    __syncthreads();
  }

  const int colbase = n0 + wn * 64;
  float* Pk = Pout + (size_t)kz * RPMAX * N_;
#pragma unroll
  for (int fm = 0; fm < FM; ++fm) {
    int rg = rowbase + wm * 64 + fm * 16 + ((lane >> 4) << 2);
#pragma unroll
    for (int j = 0; j < 4; ++j) {
#pragma unroll
      for (int fn = 0; fn < FN; ++fn) {
        int colg = colbase + fn * 16 + (lane & 15);
        Pk[(size_t)(rg + j) * N_ + colg] = acc[fm][fn][j];
      }
    }
  }
}

extern "C" void kernel_launch(void* const* d_in, const int* in_sizes, int n_in,
                              void* d_out, int out_size, void* d_ws, size_t ws_size,
                              hipStream_t stream) {
  const float* x  = (const float*)d_in[0];
  const float* sw = (const float*)d_in[1];
  const float* sb = (const float*)d_in[2];
  const float* w1 = (const float*)d_in[3];
  const float* b1 = (const float*)d_in[4];
  const float* w2 = (const float*)d_in[5];
  const float* b2 = (const float*)d_in[6];
  float* out = (float*)d_out;

  char* ws = (char*)d_ws;
  int*   off      = (int*)(ws + 0);          // 9 ints
  int*   routes   = (int*)(ws + 1024);       // 2048 ints
  int*   perm_out = (int*)(ws + 16384);      // RPMAX ints (pads -1)
  int*   perm_src = (int*)(ws + 32768);      // RPMAX ints (pads 0)
  float* probs    = (float*)(ws + 65536);    // 2048x8 fp32
  unsigned short* xbf = (unsigned short*)(ws + (1u << 20));    // 4 MB
  unsigned short* H   = (unsigned short*)(ws + (8u << 20));    // 32 MB (ends 40)
  unsigned short* xg  = (unsigned short*)(ws + (40u << 20));   // 4096x1088 bf16 = 8.9 MB
  // Wbf and P time-share [49 MB, ...): Wbf dead after gemm1s; P born at gemm2s.
  unsigned short* Wbf = (unsigned short*)(ws + (49u << 20));   // 8x1024x4864 bf16 = 76 MB
  float* P            = (float*)(ws + (49u << 20));            // 4x4096x1024 fp32 = 64 MB

  // d_out layout: final(2097152) | counts(8) | psums(8) | 0(1) | pmax(2048)
  float* out_final  = out;
  float* out_counts = out + 2097152;
  float* out_psums  = out + 2097160;
  float* out_zero   = out + 2097168;
  float* out_pmax   = out + 2097169;

  router_kernel<<<T_TOK / 4, 256, 0, stream>>>(x, sw, sb, out_pmax, routes, probs, xbf);
  plan_kernel<<<1, 256, 0, stream>>>(routes, probs, off, perm_out, perm_src,
                                     out_counts, out_psums, out_zero);
  gather_kernel<<<RPMAX / 4, 256, 0, stream>>>(xbf, off, perm_src, xg);

  // convb: W1 -> bf16 at channel-coprime pitch (wide reads, wide writes)
  convb_kernel<<<E_NUM * D_DIM, 256, 0, stream>>>(w1, Wbf);

  // GEMM1: xg x Wbf -> H (relu, bf16). 128x128, compacted grid, coprime-pitch B.
  gemm1s<D_DIM, F_DIM><<<1024, 512, 0, stream>>>(xg, Wbf, b1, off, H);
  // GEMM2: H x W2 -> fp32 partials P[4][RP][1024]. 128x256, split-K=4, compacted.
  gemm2s<F_DIM, D_DIM, 4><<<512, 512, 0, stream>>>(H, w2, off, P);
  // reduce: out[tok] = (sum_kz P + b2[e]) * pmax[tok], coalesced scatter.
  reduce_kernel<<<RPMAX, 256, 0, stream>>>(P, off, perm_out, b2, out_pmax, out_final);
}

// Round 25
// 130.880 us; speedup vs baseline: 1.1945x; 1.1862x over previous
//
#include <hip/hip_runtime.h>
#include <stdint.h>

// Problem constants (B=2,S=1024,D=1024,F=4096,E=8)
#define T_TOK 2048
#define D_DIM 1024
#define F_DIM 4096
#define E_NUM 8
#define RPMAX 4096   // max padded rows at 256-alignment
#define BK 64

typedef __attribute__((ext_vector_type(8))) short bfx8;   // 8 bf16 (4 VGPR)
typedef __attribute__((ext_vector_type(4))) float fx4;    // MFMA accum / staging

__device__ __forceinline__ unsigned short f2bf(float f) {
  union { float f; uint32_t u; } v; v.f = f;
  uint32_t u = v.u;
  u += 0x7FFFu + ((u >> 16) & 1u);   // round-to-nearest-even
  return (unsigned short)(u >> 16);
}

__device__ __forceinline__ void load_lds16(const unsigned short* g, unsigned short* l) {
  __builtin_amdgcn_global_load_lds(
      (const __attribute__((address_space(1))) void*)g,
      (__attribute__((address_space(3))) void*)l, 16, 0, 0);
}

__device__ __forceinline__ uint32_t cvtpk_bf16(float lo, float hi) {
  uint32_t d;
  asm("v_cvt_pk_bf16_f32 %0, %1, %2" : "=v"(d) : "v"(lo), "v"(hi));
  return d;
}

// ---------------- router: logits, softmax, argmax; NO global atomics ----------------
__global__ __launch_bounds__(256) void router_kernel(
    const float* __restrict__ x, const float* __restrict__ sw,
    const float* __restrict__ sb, float* __restrict__ pmax_out,
    int* __restrict__ routes, float* __restrict__ probs,
    unsigned short* __restrict__ xbf) {
  const int wave = threadIdx.x >> 6, lane = threadIdx.x & 63;
  const int t = blockIdx.x * 4 + wave;
  const float* xr = x + (size_t)t * D_DIM;
  float acc[8];
#pragma unroll
  for (int e = 0; e < 8; ++e) acc[e] = 0.f;
#pragma unroll
  for (int i = 0; i < 4; ++i) {
    const int d = i * 256 + lane * 4;
    float4 xv = *(const float4*)(xr + d);
    ushort4 h;
    h.x = f2bf(xv.x); h.y = f2bf(xv.y); h.z = f2bf(xv.z); h.w = f2bf(xv.w);
    *(ushort4*)(xbf + (size_t)t * D_DIM + d) = h;
    const float xs[4] = {xv.x, xv.y, xv.z, xv.w};
#pragma unroll
    for (int j = 0; j < 4; ++j) {
      const float4* swp = (const float4*)(sw + (size_t)(d + j) * 8);
      float4 w0 = swp[0], w1 = swp[1];
      acc[0] += xs[j] * w0.x; acc[1] += xs[j] * w0.y;
      acc[2] += xs[j] * w0.z; acc[3] += xs[j] * w0.w;
      acc[4] += xs[j] * w1.x; acc[5] += xs[j] * w1.y;
      acc[6] += xs[j] * w1.z; acc[7] += xs[j] * w1.w;
    }
  }
#pragma unroll
  for (int e = 0; e < 8; ++e) {
    float v = acc[e];
    for (int o = 32; o > 0; o >>= 1) v += __shfl_down(v, o, 64);
    acc[e] = v;
  }
  if (lane == 0) {
#pragma unroll
    for (int e = 0; e < 8; ++e) acc[e] += sb[e];
    int am = 0; float mx = acc[0];
#pragma unroll
    for (int e = 1; e < 8; ++e) if (acc[e] > mx) { mx = acc[e]; am = e; }  // first-max wins
    float p[8]; float s = 0.f;
#pragma unroll
    for (int e = 0; e < 8; ++e) { p[e] = expf(acc[e] - mx); s += p[e]; }
    float inv = 1.0f / s;
    pmax_out[t] = inv;
    routes[t] = am;
#pragma unroll
    for (int e = 0; e < 8; ++e) probs[(size_t)t * 8 + e] = p[e] * inv;
  }
}

// -------- plan: counts/psums reduce, 256-aligned offsets, perm init, scatter --------
__global__ __launch_bounds__(256) void plan_kernel(
    const int* __restrict__ routes, const float* __restrict__ probs,
    int* __restrict__ off, int* __restrict__ perm_out, int* __restrict__ perm_src,
    float* __restrict__ out_counts, float* __restrict__ out_psums,
    float* __restrict__ out_zero) {
  __shared__ int cnt[8];
  __shared__ int cur[8];
  __shared__ int offs[9];
  __shared__ float red[256][8];
  const int tid = threadIdx.x;
  if (tid < 8) cnt[tid] = 0;
  for (int i = tid; i < RPMAX; i += 256) { perm_out[i] = -1; perm_src[i] = 0; }
  __syncthreads();
  float loc[8];
#pragma unroll
  for (int e = 0; e < 8; ++e) loc[e] = 0.f;
  for (int t = tid; t < T_TOK; t += 256) {
    atomicAdd(&cnt[routes[t]], 1);
    const float4* p = (const float4*)(probs + (size_t)t * 8);
    float4 a = p[0], b = p[1];
    loc[0] += a.x; loc[1] += a.y; loc[2] += a.z; loc[3] += a.w;
    loc[4] += b.x; loc[5] += b.y; loc[6] += b.z; loc[7] += b.w;
  }
#pragma unroll
  for (int e = 0; e < 8; ++e) red[tid][e] = loc[e];
  __syncthreads();
  for (int s = 128; s >= 1; s >>= 1) {
    if (tid < s) {
#pragma unroll
      for (int e = 0; e < 8; ++e) red[tid][e] += red[tid + s][e];
    }
    __syncthreads();
  }
  if (tid == 0) {
    int o = 0;
    for (int e = 0; e < 8; ++e) { offs[e] = o; o += ((cnt[e] + 255) >> 8) << 8; }
    offs[8] = o;
    *out_zero = 0.0f;
  }
  __syncthreads();
  if (tid < 9) off[tid] = offs[tid];
  if (tid < 8) {
    cur[tid] = offs[tid];
    out_counts[tid] = (float)cnt[tid];
    out_psums[tid] = red[0][tid];
  }
  __syncthreads();
  for (int t = tid; t < T_TOK; t += 256) {
    int e = routes[t];
    int pos = atomicAdd(&cur[e], 1);
    perm_out[pos] = t;
    perm_src[pos] = t;
  }
}

// ---------------- gather: xg[slot] = xbf[perm_src[slot]] ----------------
__global__ __launch_bounds__(256) void gather_kernel(
    const unsigned short* __restrict__ xbf, const int* __restrict__ off,
    const int* __restrict__ perm_src, unsigned short* __restrict__ xg) {
  const int wave = threadIdx.x >> 6, lane = threadIdx.x & 63;
  const int row = blockIdx.x * 4 + wave;
  if (row >= off[8]) return;
  const int tok = perm_src[row];
  const bfx8* s = (const bfx8*)(xbf + (size_t)tok * D_DIM);
  bfx8* d = (bfx8*)(xg + (size_t)row * D_DIM);
  d[lane] = s[lane];
  d[lane + 64] = s[lane + 64];
}

// ---------------- reduce: out[tok] = (sum_kz P[kz][row] + b2[e]) * pmax[tok] ----------
__global__ __launch_bounds__(256) void reduce_kernel(
    const float* __restrict__ P, const int* __restrict__ off,
    const int* __restrict__ perm_out, const float* __restrict__ b2,
    const float* __restrict__ pmax, float* __restrict__ out) {
  const int row = blockIdx.x;
  if (row >= off[8]) return;
  const int tok = perm_out[row];
  if (tok < 0) return;
  int e = 0;
#pragma unroll
  for (int i = 1; i <= 7; ++i) if (row >= off[i]) e = i;
  const int col = threadIdx.x * 4;
  const size_t base = (size_t)row * D_DIM + col;
  float4 p0 = *(const float4*)(P + base);
  float4 p1 = *(const float4*)(P + (size_t)1 * RPMAX * D_DIM + base);
  float4 p2 = *(const float4*)(P + (size_t)2 * RPMAX * D_DIM + base);
  float4 p3 = *(const float4*)(P + (size_t)3 * RPMAX * D_DIM + base);
  float4 bv = *(const float4*)(b2 + (size_t)e * D_DIM + col);
  const float pm = pmax[tok];
  float4 r;
  r.x = (p0.x + p1.x + p2.x + p3.x + bv.x) * pm;
  r.y = (p0.y + p1.y + p2.y + p3.y + bv.y) * pm;
  r.z = (p0.z + p1.z + p2.z + p3.z + bv.z) * pm;
  r.w = (p0.w + p1.w + p2.w + p3.w + bv.w) * pm;
  *(float4*)(out + (size_t)tok * D_DIM + col) = r;
}

// ---------------- GEMM1: 128x256 single-buffer, 48KB LDS, fused fp32-B ----------------
// 8 waves (2m x 4n), wave 64x64, m97 loop (STAGE -> barrier -> COMPUTE -> barrier);
// co-resident sibling block's COMPUTE hides memory phases (m114). A = xg bf16 DMA;
// B = W1 fp32 -> cvt_pk bf16 -> swizzled ds_write. Epilogue: relu(acc+b1) -> H bf16.
template <int K_, int N_>
__global__ __launch_bounds__(512, 4) void gemm1s(
    const unsigned short* __restrict__ A,    // xg [RP][K_]
    const float* __restrict__ W,             // [E][K_][N_] fp32
    const float* __restrict__ Bias,          // [E][N_]
    const int* __restrict__ off,
    unsigned short* __restrict__ Hout) {
  constexpr int BM = 128, BN = 256;
  constexpr int NT = K_ / BK;                // 16
  constexpr int FM = 4, FN = 4, GRP = 2;
  constexpr int NBX = N_ / BN;               // 16
  __shared__ __align__(16) unsigned short As[BM * 64];   // 16 KB
  __shared__ __align__(16) unsigned short Bs[BN * 64];   // 32 KB
  const int tid = threadIdx.x;
  const int nby = gridDim.y;
  const int lin = blockIdx.y * NBX + blockIdx.x;
  const int total = NBX * nby;
  const int newlin = (lin & 7) * (total >> 3) + (lin >> 3);
  const int bx = newlin / nby;
  const int by = newlin % nby;
  const int rowbase = by * BM;
  if (rowbase >= off[8]) return;
  int e = 0;
#pragma unroll
  for (int i = 1; i <= 7; ++i) if (rowbase >= off[i]) e = i;
  const int n0 = bx * BN;
  const int wave = tid >> 6, lane = tid & 63;
  const int wm = wave >> 2, wn = wave & 3;
  const float* Wn0 = W + (size_t)e * K_ * N_ + n0;

  const unsigned short* aSrc[2];
#pragma unroll
  for (int c = 0; c < 2; ++c) {
    int ca = (wave * 2 + c) * 64 + lane;
    int row = ca >> 3, slot = ca & 7;
    int sc = slot ^ (row & 7);
    aSrc[c] = A + (size_t)(rowbase + row) * K_ + sc * 8;
  }

  const int nq = lane & 15;
  const int qg = lane >> 4;
  const int kq = (qg & 1) * 4;
  fx4 br[GRP][4];

  fx4 acc[FM][FN];
#pragma unroll
  for (int a = 0; a < FM; ++a)
#pragma unroll
    for (int b = 0; b < FN; ++b) acc[a][b] = (fx4){0.f, 0.f, 0.f, 0.f};

  for (int t = 0; t < NT; ++t) {
    const int kt = t * BK;
#pragma unroll
    for (int c = 0; c < 2; ++c)
      load_lds16(aSrc[c] + kt, As + (wave * 2 + c) * 512);
#pragma unroll
    for (int g = 0; g < GRP; ++g) {
      const int cb = g * 2 + (qg >> 1);
#pragma unroll
      for (int j = 0; j < 4; ++j)
        br[g][j] = *(const fx4*)(Wn0 + (size_t)(kt + wave * 8 + kq + j) * N_ +
                                 cb * 64 + nq * 4);
    }
#pragma unroll
    for (int g = 0; g < GRP; ++g) {
      const int cb = g * 2 + (qg >> 1);
#pragma unroll
      for (int i = 0; i < 4; ++i) {
        const int nl = cb * 64 + nq * 4 + i;
        const int key = ((nl >> 2) + 2 * (nl & 3)) & 7;
        uint32_t d0 = cvtpk_bf16(br[g][0][i], br[g][1][i]);
        uint32_t d1 = cvtpk_bf16(br[g][2][i], br[g][3][i]);
        *(uint2*)(Bs + nl * 64 + (wave ^ key) * 8 + kq) = make_uint2(d0, d1);
      }
    }
    __syncthreads();
#pragma unroll
    for (int kk = 0; kk < 2; ++kk) {
      bfx8 af[FM], bf[FN];
#pragma unroll
      for (int fm = 0; fm < FM; ++fm) {
        int r = wm * 64 + fm * 16 + (lane & 15);
        int c = (kk * 4 + (lane >> 4)) ^ (r & 7);
        af[fm] = *(const bfx8*)(As + r * 64 + c * 8);
      }
#pragma unroll
      for (int fn = 0; fn < FN; ++fn) {
        int nn = wn * 64 + fn * 16 + (lane & 15);
        int key = ((nn >> 2) + 2 * (nn & 3)) & 7;
        int c = (kk * 4 + (lane >> 4)) ^ key;
        bf[fn] = *(const bfx8*)(Bs + nn * 64 + c * 8);
      }
#pragma unroll
      for (int fm = 0; fm < FM; ++fm)
#pragma unroll
        for (int fn = 0; fn < FN; ++fn)
          acc[fm][fn] = __builtin_amdgcn_mfma_f32_16x16x32_bf16(
              af[fm], bf[fn], acc[fm][fn], 0, 0, 0);
    }
    __syncthreads();
  }

  // ---- epilogue: relu(acc + b1) -> H bf16 ----
  const int colbase = n0 + wn * 64;
#pragma unroll
  for (int fn = 0; fn < FN; ++fn) {
    int colg = colbase + fn * 16 + (lane & 15);
    float bv = Bias[(size_t)e * N_ + colg];
#pragma unroll
    for (int fm = 0; fm < FM; ++fm) {
      int rg = rowbase + wm * 64 + fm * 16 + ((lane >> 4) << 2);
#pragma unroll
      for (int j = 0; j < 4; ++j) {
        float v = fmaxf(acc[fm][fn][j] + bv, 0.f);
        Hout[(size_t)(rg + j) * N_ + colg] = f2bf(v);
      }
    }
  }
}

// ---------------- GEMM2: 128x256 single-buffer, 48KB LDS, fused fp32-B (R18) ---------
template <int K_, int N_, int KSPLIT>
__global__ __launch_bounds__(512, 4) void gemm2s(
    const unsigned short* __restrict__ A,    // H [RP][K_]
    const float* __restrict__ W,             // [E][K_][N_] fp32
    const int* __restrict__ off,
    float* __restrict__ Pout) {
  constexpr int BM = 128, BN = 256;
  constexpr int KS = K_ / KSPLIT;
  constexpr int NT = KS / BK;
  constexpr int FM = 4, FN = 4, GRP = 2;
  constexpr int NBX = N_ / BN;
  __shared__ __align__(16) unsigned short As[BM * 64];   // 16 KB
  __shared__ __align__(16) unsigned short Bs[BN * 64];   // 32 KB
  const int tid = threadIdx.x;
  const int nby = gridDim.y;
  const int lin = (blockIdx.z * nby + blockIdx.y) * NBX + blockIdx.x;
  const int total = NBX * nby * KSPLIT;
  const int newlin = (lin & 7) * (total >> 3) + (lin >> 3);
  const int bx = newlin / (nby * KSPLIT);
  const int rem = newlin % (nby * KSPLIT);
  const int by = rem % nby;
  const int kz = rem / nby;
  const int rowbase = by * BM;
  if (rowbase >= off[8]) return;
  int e = 0;
#pragma unroll
  for (int i = 1; i <= 7; ++i) if (rowbase >= off[i]) e = i;
  const int n0 = bx * BN;
  const int k0base = kz * KS;
  const int wave = tid >> 6, lane = tid & 63;
  const int wm = wave >> 2, wn = wave & 3;
  const float* Wn0 = W + (size_t)e * K_ * N_ + n0;

  const unsigned short* aSrc[2];
#pragma unroll
  for (int c = 0; c < 2; ++c) {
    int ca = (wave * 2 + c) * 64 + lane;
    int row = ca >> 3, slot = ca & 7;
    int sc = slot ^ (row & 7);
    aSrc[c] = A + (size_t)(rowbase + row) * K_ + k0base + sc * 8;
  }

  const int nq = lane & 15;
  const int qg = lane >> 4;
  const int kq = (qg & 1) * 4;
  fx4 br[GRP][4];

  fx4 acc[FM][FN];
#pragma unroll
  for (int a = 0; a < FM; ++a)
#pragma unroll
    for (int b = 0; b < FN; ++b) acc[a][b] = (fx4){0.f, 0.f, 0.f, 0.f};

  for (int t = 0; t < NT; ++t) {
    const int kt = t * BK;
#pragma unroll
    for (int c = 0; c < 2; ++c)
      load_lds16(aSrc[c] + kt, As + (wave * 2 + c) * 512);
#pragma unroll
    for (int g = 0; g < GRP; ++g) {
      const int cb = g * 2 + (qg >> 1);
#pragma unroll
      for (int j = 0; j < 4; ++j)
        br[g][j] = *(const fx4*)(Wn0 + (size_t)(kt + wave * 8 + kq + j) * N_ +
                                 cb * 64 + nq * 4);
    }
#pragma unroll
    for (int g = 0; g < GRP; ++g) {
      const int cb = g * 2 + (qg >> 1);
#pragma unroll
      for (int i = 0; i < 4; ++i) {
        const int nl = cb * 64 + nq * 4 + i;
        const int key = ((nl >> 2) + 2 * (nl & 3)) & 7;
        uint32_t d0 = cvtpk_bf16(br[g][0][i], br[g][1][i]);
        uint32_t d1 = cvtpk_bf16(br[g][2][i], br[g][3][i]);
        *(uint2*)(Bs + nl * 64 + (wave ^ key) * 8 + kq) = make_uint2(d0, d1);
      }
    }
    __syncthreads();
#pragma unroll
    for (int kk = 0; kk < 2; ++kk) {
      bfx8 af[FM], bf[FN];
#pragma unroll
      for (int fm = 0; fm < FM; ++fm) {
        int r = wm * 64 + fm * 16 + (lane & 15);
        int c = (kk * 4 + (lane >> 4)) ^ (r & 7);
        af[fm] = *(const bfx8*)(As + r * 64 + c * 8);
      }
#pragma unroll
      for (int fn = 0; fn < FN; ++fn) {
        int nn = wn * 64 + fn * 16 + (lane & 15);
        int key = ((nn >> 2) + 2 * (nn & 3)) & 7;
        int c = (kk * 4 + (lane >> 4)) ^ key;
        bf[fn] = *(const bfx8*)(Bs + nn * 64 + c * 8);
      }
#pragma unroll
      for (int fm = 0; fm < FM; ++fm)
#pragma unroll
        for (int fn = 0; fn < FN; ++fn)
          acc[fm][fn] = __builtin_amdgcn_mfma_f32_16x16x32_bf16(
              af[fm], bf[fn], acc[fm][fn], 0, 0, 0);
    }
    __syncthreads();
  }

  const int colbase = n0 + wn * 64;
  float* Pk = Pout + (size_t)kz * RPMAX * N_;
#pragma unroll
  for (int fm = 0; fm < FM; ++fm) {
    int rg = rowbase + wm * 64 + fm * 16 + ((lane >> 4) << 2);
#pragma unroll
    for (int j = 0; j < 4; ++j) {
#pragma unroll
      for (int fn = 0; fn < FN; ++fn) {
        int colg = colbase + fn * 16 + (lane & 15);
        Pk[(size_t)(rg + j) * N_ + colg] = acc[fm][fn][j];
      }
    }
  }
}

extern "C" void kernel_launch(void* const* d_in, const int* in_sizes, int n_in,
                              void* d_out, int out_size, void* d_ws, size_t ws_size,
                              hipStream_t stream) {
  const float* x  = (const float*)d_in[0];
  const float* sw = (const float*)d_in[1];
  const float* sb = (const float*)d_in[2];
  const float* w1 = (const float*)d_in[3];
  const float* b1 = (const float*)d_in[4];
  const float* w2 = (const float*)d_in[5];
  const float* b2 = (const float*)d_in[6];
  float* out = (float*)d_out;

  char* ws = (char*)d_ws;
  int*   off      = (int*)(ws + 0);          // 9 ints
  int*   routes   = (int*)(ws + 1024);       // 2048 ints
  int*   perm_out = (int*)(ws + 16384);      // RPMAX ints (pads -1)
  int*   perm_src = (int*)(ws + 32768);      // RPMAX ints (pads 0)
  float* probs    = (float*)(ws + 65536);    // 2048x8 fp32
  unsigned short* xbf = (unsigned short*)(ws + (1u << 20));   // 4 MB
  unsigned short* H   = (unsigned short*)(ws + (8u << 20));   // 32 MB
  unsigned short* xg  = (unsigned short*)(ws + (40u << 20));  // 8 MB
  float* P            = (float*)(ws + (48u << 20));           // 64 MB

  // d_out layout: final(2097152) | counts(8) | psums(8) | 0(1) | pmax(2048)
  float* out_final  = out;
  float* out_counts = out + 2097152;
  float* out_psums  = out + 2097160;
  float* out_zero   = out + 2097168;
  float* out_pmax   = out + 2097169;

  router_kernel<<<T_TOK / 4, 256, 0, stream>>>(x, sw, sb, out_pmax, routes, probs, xbf);
  plan_kernel<<<1, 256, 0, stream>>>(routes, probs, off, perm_out, perm_src,
                                     out_counts, out_psums, out_zero);
  gather_kernel<<<RPMAX / 4, 256, 0, stream>>>(xbf, off, perm_src, xg);

  // GEMM1: xg[RP,1024] x W1 -> H (relu, bf16). 128x256 single-buffer, 48KB LDS,
  // grid 16x32=512 blocks (2/CU), n-chunked XCD swizzle.
  gemm1s<D_DIM, F_DIM>
      <<<dim3(F_DIM / 256, RPMAX / 128, 1), 512, 0, stream>>>(
          xg, w1, b1, off, H);
  // GEMM2: H[RP,4096] x W2 -> fp32 partials P[4][RP][1024]. 128x256 single-buffer,
  // split-K=4, grid 4x32x4=512 blocks (2/CU exact).
  gemm2s<F_DIM, D_DIM, 4>
      <<<dim3(D_DIM / 256, RPMAX / 128, 4), 512, 0, stream>>>(H, w2, off, P);
  // reduce: out[tok] = (sum_kz P + b2[e]) * pmax[tok], coalesced scatter.
  reduce_kernel<<<RPMAX, 256, 0, stream>>>(P, off, perm_out, b2, out_pmax, out_final);
}